// Round 2
// baseline (2916.466 us; speedup 1.0000x reference)
//
#include <hip/hip_runtime.h>

#define BATCH   8192
#define DIMN    64
#define HIDN    128
#define NSTEPS  100
#define RT      32          // rows per block
#define DT      0.01f
#define SQDT    0.1f        // sqrt(0.01f) rounds to 0.1f exactly in fp32

__device__ __forceinline__ float fast_tanh(float a) {
    float e = __expf(2.0f * a);
    return 1.0f - 2.0f * __builtin_amdgcn_rcpf(e + 1.0f);
}

// 512 threads = 8 waves: waves 0-3 drift MLP, waves 4-7 diffusion MLP.
// Wave w handles rows r0..r0+7 (r0 = (w&3)*8); lane spans output columns.
// Layer-1: acc over n = {lane, lane+64}; x read as wave-uniform b128 broadcast.
// Layer-2: W2[k][lane] pinned in 128 VGPRs; h read as wave-uniform b128
// broadcast from the wave's OWN h tile (wave-private -> no A/B barrier).
__global__ __launch_bounds__(512, 2)
void sde_kernel(const float* __restrict__ x0,
                const float* __restrict__ noise,
                const float* __restrict__ Wd1, const float* __restrict__ bd1,
                const float* __restrict__ Wd2, const float* __restrict__ bd2,
                const float* __restrict__ Wg1, const float* __restrict__ bg1,
                const float* __restrict__ Wg2, const float* __restrict__ bg2,
                float* __restrict__ out)
{
    // 64K(W1) + 32K(h) + 8K(x) + 8K(f) + 1.5K(bias) = 113.5 KiB -> 1 block/CU, 8 waves/CU
    __shared__ float sW1[2][DIMN * HIDN];   // [d,g][k][n] row-major, n stride 128
    __shared__ float sh[2][RT * HIDN];      // tanh(h) tiles, wave-private rows
    __shared__ float sx[RT * DIMN];
    __shared__ float sf[RT * DIMN];         // dt * f, drift -> diffusion handoff
    __shared__ float sb1[2][HIDN];
    __shared__ float sb2[2][DIMN];

    const int t    = threadIdx.x;
    const int lane = t & 63;
    const int wv   = t >> 6;        // 0..7
    const int half = wv >> 2;       // 0 = drift, 1 = diffusion
    const int r0   = (wv & 3) * 8;
    const long row0 = (long)blockIdx.x * RT;

    // ---- stage layer-1 weights + biases ----
    for (int i = t; i < DIMN * HIDN / 4; i += 512) {
        ((float4*)sW1[0])[i] = ((const float4*)Wd1)[i];
        ((float4*)sW1[1])[i] = ((const float4*)Wg1)[i];
    }
    if (t < HIDN)               { sb1[0][t] = bd1[t]; sb1[1][t] = bg1[t]; }
    else if (t < HIDN + DIMN)   { int j = t - HIDN; sb2[0][j] = bd2[j]; sb2[1][j] = bg2[j]; }

    // ---- x0 -> sx, out[0] = x0 ----
    for (int i = t; i < RT * DIMN / 4; i += 512) {
        float4 v = ((const float4*)(x0 + row0 * DIMN))[i];
        ((float4*)sx)[i] = v;
        ((float4*)(out + row0 * DIMN))[i] = v;
    }

    // ---- layer-2 weight column pinned in registers: W2[k][lane], k=0..127 ----
    const float* W2g = half ? Wg2 : Wd2;
    float w2r[HIDN];
    #pragma unroll
    for (int k = 0; k < HIDN; ++k) w2r[k] = W2g[k * DIMN + lane];

    __syncthreads();

    const float* sW1h = sW1[half];
    float*       shh  = sh[half];
    const float b1a = sb1[half][lane];
    const float b1b = sb1[half][64 + lane];
    const float b2v = sb2[half][lane];

    float xn[8];   // diffusion: trajectory values pending store
    float dw[8];

    for (int s = 0; s < NSTEPS; ++s) {
        // ---- overlapped with phase A: store prev traj row, prefetch noise ----
        if (half) {
            if (s > 0) {
                float* op = out + ((long)s * BATCH + row0 + r0) * DIMN + lane;
                #pragma unroll
                for (int r = 0; r < 8; ++r) op[r * DIMN] = xn[r];
            }
            const float* np = noise + ((long)s * BATCH + row0 + r0) * DIMN + lane;
            #pragma unroll
            for (int r = 0; r < 8; ++r) dw[r] = np[r * DIMN];
        }

        // ---------- Phase A: h = tanh(x @ W1 + b1) ----------
        float acc0[8], acc1[8];
        #pragma unroll
        for (int r = 0; r < 8; ++r) { acc0[r] = b1a; acc1[r] = b1b; }
        #pragma unroll
        for (int k = 0; k < DIMN; k += 4) {
            // per-lane weight reads: bank = lane%32, 2-way wave aliasing = free
            float wa0 = sW1h[(k+0)*HIDN + lane], wb0 = sW1h[(k+0)*HIDN + 64 + lane];
            float wa1 = sW1h[(k+1)*HIDN + lane], wb1 = sW1h[(k+1)*HIDN + 64 + lane];
            float wa2 = sW1h[(k+2)*HIDN + lane], wb2 = sW1h[(k+2)*HIDN + 64 + lane];
            float wa3 = sW1h[(k+3)*HIDN + lane], wb3 = sW1h[(k+3)*HIDN + 64 + lane];
            #pragma unroll
            for (int r = 0; r < 8; ++r) {
                float4 xv = *(const float4*)&sx[(r0 + r) * DIMN + k];  // uniform broadcast
                acc0[r] = fmaf(xv.x, wa0, acc0[r]);
                acc0[r] = fmaf(xv.y, wa1, acc0[r]);
                acc0[r] = fmaf(xv.z, wa2, acc0[r]);
                acc0[r] = fmaf(xv.w, wa3, acc0[r]);
                acc1[r] = fmaf(xv.x, wb0, acc1[r]);
                acc1[r] = fmaf(xv.y, wb1, acc1[r]);
                acc1[r] = fmaf(xv.z, wb2, acc1[r]);
                acc1[r] = fmaf(xv.w, wb3, acc1[r]);
            }
        }
        #pragma unroll
        for (int r = 0; r < 8; ++r) {
            shh[(r0 + r) * HIDN + lane]      = fast_tanh(acc0[r]);
            shh[(r0 + r) * HIDN + 64 + lane] = fast_tanh(acc1[r]);
        }
        // no barrier: h tile rows are wave-private (written and read by same wave)

        // ---------- Phase B: y = tanh_h @ W2 + b2 ----------
        float acc2[8];
        #pragma unroll
        for (int r = 0; r < 8; ++r) acc2[r] = b2v;
        #pragma unroll
        for (int k = 0; k < HIDN; k += 4) {
            #pragma unroll
            for (int r = 0; r < 8; ++r) {
                float4 hv = *(const float4*)&shh[(r0 + r) * HIDN + k];  // uniform broadcast
                acc2[r] = fmaf(hv.x, w2r[k+0], acc2[r]);
                acc2[r] = fmaf(hv.y, w2r[k+1], acc2[r]);
                acc2[r] = fmaf(hv.z, w2r[k+2], acc2[r]);
                acc2[r] = fmaf(hv.w, w2r[k+3], acc2[r]);
            }
        }
        if (!half) {
            #pragma unroll
            for (int r = 0; r < 8; ++r) sf[(r0 + r) * DIMN + lane] = DT * acc2[r];
        }
        __syncthreads();   // #1: drift's sf/x ordering vs diffusion's C reads

        // ---------- Phase C (diffusion): x += dt*f + sqrt_dt*dw*g ----------
        if (half) {
            #pragma unroll
            for (int r = 0; r < 8; ++r) {
                float xv = sx[(r0 + r) * DIMN + lane];
                float v  = xv + sf[(r0 + r) * DIMN + lane] + SQDT * dw[r] * acc2[r];
                xn[r] = v;
                sx[(r0 + r) * DIMN + lane] = v;
            }
        }
        __syncthreads();   // #2: x update visible to next step's phase A
    }

    if (half) {
        float* op = out + ((long)NSTEPS * BATCH + row0 + r0) * DIMN + lane;
        #pragma unroll
        for (int r = 0; r < 8; ++r) op[r * DIMN] = xn[r];
    }
}

extern "C" void kernel_launch(void* const* d_in, const int* in_sizes, int n_in,
                              void* d_out, int out_size, void* d_ws, size_t ws_size,
                              hipStream_t stream) {
    const float* x0    = (const float*)d_in[0];
    // d_in[1] = t_span (unused)
    const float* noise = (const float*)d_in[2];
    const float* Wd1   = (const float*)d_in[3];
    const float* bd1   = (const float*)d_in[4];
    const float* Wd2   = (const float*)d_in[5];
    const float* bd2   = (const float*)d_in[6];
    const float* Wg1   = (const float*)d_in[7];
    const float* bg1   = (const float*)d_in[8];
    const float* Wg2   = (const float*)d_in[9];
    const float* bg2   = (const float*)d_in[10];
    float* out = (float*)d_out;

    sde_kernel<<<BATCH / RT, 512, 0, stream>>>(
        x0, noise, Wd1, bd1, Wd2, bd2, Wg1, bg1, Wg2, bg2, out);
}